// Round 8
// baseline (112.985 us; speedup 1.0000x reference)
//
#include <hip/hip_runtime.h>
#include <hip/hip_bf16.h>
#include <math.h>

#define B 8
#define N 2048
#define F_IN 128
#define F_OUT 64
#define ALPHA 0.2f
#define LOG2E 1.4426950408889634f

#if __has_builtin(__builtin_amdgcn_exp2f)
#define EXP2F(x) __builtin_amdgcn_exp2f(x)
#else
#define EXP2F(x) exp2f(x)
#endif

typedef _Float16 half8 __attribute__((ext_vector_type(8)));
typedef float f32x4 __attribute__((ext_vector_type(4)));

// ---------------------------------------------------------------------------
// Kernel A (fused): blocks [0,N) -> adj bitmask; blocks [N, N+B*N/16) ->
// Wh via MFMA into Wpack fragment order + f/g (fp32 exact via in-block wa).
// ---------------------------------------------------------------------------
__global__ __launch_bounds__(256) void fused_pre_kernel(
    const float* __restrict__ adj, unsigned* __restrict__ bits,
    const float* __restrict__ h, const float* __restrict__ W,
    const float* __restrict__ a, _Float16* __restrict__ Wpack,
    float* __restrict__ fv, float* __restrict__ gv)
{
    const int tid = threadIdx.x;

    __shared__ float hs[16 * 132];   // 8.4 KB (wh_fg path)
    __shared__ float was[256];       // wa1[128] ++ wa2[128]

    if (blockIdx.x < N) {
        // ---- bitmask path ----
        const int i = blockIdx.x;
        const int lane = tid & 63;
        const int w = tid >> 6;
        const float* row = adj + (size_t)i * N;
#pragma unroll
        for (int jt = 0; jt < 8; ++jt) {
            float v = row[jt * 256 + tid];
            unsigned long long m = __ballot(v > 0.f);
            if (lane == 0) {
                bits[i * 64 + jt * 8 + w * 2]     = (unsigned)m;
                bits[i * 64 + jt * 8 + w * 2 + 1] = (unsigned)(m >> 32);
            }
        }
        return;
    }

    // ---- wh_fg path ----
    const int blk  = blockIdx.x - N;   // 0..1023, covers 16 h-rows
    const int w    = tid >> 6;         // wave = feature group fg
    const int lane = tid & 63;
    const int mrow = lane & 15;
    const int quad = lane >> 4;

    // stage 16 h-rows (8 KB) coalesced
    const float4* h4 = (const float4*)(h + (size_t)blk * 16 * F_IN);
#pragma unroll
    for (int s = 0; s < 2; ++s) {
        int idx = s * 256 + tid;
        *(float4*)&hs[(idx >> 5) * 132 + (idx & 31) * 4] = h4[idx];
    }

    // wa (fp32, same summation order as before): thread (arr, k)
    {
        const int k = tid & 127;
        const float* ap = a + (tid >> 7) * 64;
        const float* wr = W + k * 64;
        float s = 0.f;
#pragma unroll
        for (int f = 0; f < 64; ++f) s += wr[f] * ap[f];
        was[(tid >> 7) * 128 + k] = s;
    }

    // W fragments direct from global (L2-hot):
    // wF[ks][slot] = W[ks*32 + quad*8 + slot][w*16 + mrow]
    half8 wF[4];
#pragma unroll
    for (int ks = 0; ks < 4; ++ks)
#pragma unroll
        for (int slot = 0; slot < 8; ++slot)
            wF[ks][slot] = (_Float16)W[(ks * 32 + quad * 8 + slot) * 64 + w * 16 + mrow];

    __syncthreads();

    const int jgl = blk * 16;
    const int b   = jgl >> 11;
    const int jb  = jgl & (N - 1);
    const float* hrow = &hs[mrow * 132];

    // MFMA: A row = mrow (h-row), k = ks*32 + quad*8 + t
    f32x4 acc = {0.f, 0.f, 0.f, 0.f};
#pragma unroll
    for (int ks = 0; ks < 4; ++ks) {
        const float* hp = hrow + ks * 32 + quad * 8;
        float4 x0 = *(const float4*)hp;
        float4 x1 = *(const float4*)(hp + 4);
        half8 aF;
#pragma unroll
        for (int t = 0; t < 4; ++t) {
            aF[t]     = (_Float16)((const float*)&x0)[t];
            aF[4 + t] = (_Float16)((const float*)&x1)[t];
        }
        acc = __builtin_amdgcn_mfma_f32_16x16x32_f16(aF, wF[ks], acc, 0, 0, 0);
    }

    // f/g: wave 0 only; row = mrow, k-chunk = quad*32 (fp32 exact)
    if (w == 0) {
        const float* hp = hrow + quad * 32;
        const float* w1 = &was[quad * 32];
        const float* w2 = &was[128 + quad * 32];
        float s1 = 0.f, s2 = 0.f;
#pragma unroll
        for (int t = 0; t < 32; ++t) {
            float hv = hp[t];
            s1 += hv * w1[t];
            s2 += hv * w2[t];
        }
        s1 += __shfl_xor(s1, 16, 64); s1 += __shfl_xor(s1, 32, 64);
        s2 += __shfl_xor(s2, 16, 64); s2 += __shfl_xor(s2, 32, 64);
        if (lane < 16) {
            fv[(size_t)b * N + jb + lane] = s1;
            gv[(size_t)b * N + jb + lane] = s2;
        }
    }

    // store Wpack: j = jb + quad*4 + reg, f = w*16 + mrow
    const int m     = jb >> 7;
    const int q     = (jb >> 5) & 3;
    const int jg    = (jb & 31) + quad * 4;
    const int flane = ((jg >> 3) & 3) * 16 + mrow;
    const int slot  = jg & 7;
    _Float16* base = Wpack + ((((size_t)b * 16 + m) * 4 + q) * 4 + w) * 512
                     + (size_t)flane * 8 + slot;
    union { _Float16 hh[4]; ushort4 u; } pk;
#pragma unroll
    for (int reg = 0; reg < 4; ++reg) pk.hh[reg] = (_Float16)acc[reg];
    *(ushort4*)(base) = pk.u;
}

// ---------------------------------------------------------------------------
// Kernel B: barrier-free MFMA aggregation. exp2-domain softmax (f,g,m
// pre-scaled by log2e; leaky commutes with positive scale) + row-sums via
// ones-column MFMA (identical f16-rounded summands, fp32 accumulate).
// ---------------------------------------------------------------------------
#define MSTR 68
#define RSTR 68

__global__ __launch_bounds__(256) void attn_mfma_kernel(
    const _Float16* __restrict__ Wpack, const float* __restrict__ fv,
    const float* __restrict__ gv, const unsigned* __restrict__ bits,
    float* __restrict__ out)
{
    const int i0 = blockIdx.x * 32;
    const int b  = blockIdx.y;
    const int tid  = threadIdx.x;
    const int lane = tid & 63;
    const int wsl  = tid >> 6;
    const int mrow = lane & 15;
    const int quad = lane >> 4;

    __shared__ __align__(16) float    gs[N];
    __shared__ float    fs[32];
    __shared__ float    ms[32];
    __shared__ __align__(16) unsigned mws[32 * MSTR];
    __shared__ float    redacc[4 * 32 * RSTR];
    __shared__ float    rsp[4 * 32];

    // stage g (pre-scaled by log2e), f (scaled), mask words
    const float4* g4 = (const float4*)(gv + (size_t)b * N);
#pragma unroll
    for (int s = 0; s < 2; ++s) {
        float4 gvv = g4[tid + s * 256];
        gvv.x *= LOG2E; gvv.y *= LOG2E; gvv.z *= LOG2E; gvv.w *= LOG2E;
        ((float4*)gs)[tid + s * 256] = gvv;
    }
    if (tid < 32) fs[tid] = fv[(size_t)b * N + i0 + tid] * LOG2E;
#pragma unroll
    for (int s = 0; s < 2; ++s) {
        const int idx = tid + s * 256;
        const int i   = idx >> 4;
        const int w4  = (idx & 15) * 4;
        *(uint4*)&mws[i * MSTR + w4] =
            *(const uint4*)&bits[(size_t)(i0 + i) * 64 + w4];
    }
    __syncthreads();

    // per-row masked max of scaled g; ms = leaky(f+gmax) in scaled domain
#pragma unroll
    for (int rr = 0; rr < 2; ++rr) {
        const int ii = rr * 16 + (tid >> 4);
        const int jj = tid & 15;
        float gmax = -INFINITY;
#pragma unroll
        for (int t = 0; t < 4; ++t) {
            unsigned mw = mws[ii * MSTR + jj * 4 + t];
            const int jb = jj * 128 + t * 32;
            while (mw) {
                int bit = __builtin_ctz(mw);
                gmax = fmaxf(gmax, gs[jb + bit]);
                mw &= mw - 1;
            }
        }
#pragma unroll
        for (int off = 8; off >= 1; off >>= 1)
            gmax = fmaxf(gmax, __shfl_down(gmax, off, 16));
        if (jj == 0) {
            float m = fs[ii] + gmax;
            ms[ii] = (m > 0.f) ? m : ALPHA * m;
        }
    }
    __syncthreads();

    const float fi0 = fs[mrow],      mi0 = ms[mrow];
    const float fi1 = fs[16 + mrow], mi1 = ms[16 + mrow];
    const _Float16* wpb = Wpack + (size_t)b * 131072;

    half8 ones;
#pragma unroll
    for (int t = 0; t < 8; ++t) ones[t] = (_Float16)1.0f;

    f32x4 a00 = {0,0,0,0}, a01 = {0,0,0,0}, a02 = {0,0,0,0}, a03 = {0,0,0,0};
    f32x4 a10 = {0,0,0,0}, a11 = {0,0,0,0}, a12 = {0,0,0,0}, a13 = {0,0,0,0};
    f32x4 s0acc = {0,0,0,0}, s1acc = {0,0,0,0};

    for (int mm = 0; mm < 4; ++mm) {
        const int m  = wsl * 4 + mm;
        const uint4 mv0 = *(const uint4*)&mws[mrow * MSTR + m * 4];
        const uint4 mv1 = *(const uint4*)&mws[(16 + mrow) * MSTR + m * 4];
#pragma unroll
        for (int q = 0; q < 4; ++q) {
            const int jb = m * 128 + q * 32 + quad * 8;
            const _Float16* tb = wpb + (size_t)(m * 4 + q) * 2048 + lane * 8;

            half8 b0 = *(const half8*)(tb);
            half8 b1 = *(const half8*)(tb + 512);
            half8 b2 = *(const half8*)(tb + 1024);
            half8 b3 = *(const half8*)(tb + 1536);

            const unsigned w0 = (q == 0) ? mv0.x : (q == 1) ? mv0.y
                               : (q == 2) ? mv0.z : mv0.w;
            const unsigned w1 = (q == 0) ? mv1.x : (q == 1) ? mv1.y
                               : (q == 2) ? mv1.z : mv1.w;
            const unsigned mb0 = (w0 >> (quad * 8)) & 0xFFu;
            const unsigned mb1 = (w1 >> (quad * 8)) & 0xFFu;

            float4 ga = *(const float4*)&gs[jb];
            float4 gb = *(const float4*)&gs[jb + 4];
            half8 aF0, aF1;
#pragma unroll
            for (int t = 0; t < 8; ++t) {
                float g = (t < 4) ? ((const float*)&ga)[t]
                                  : ((const float*)&gb)[t - 4];
                float s0 = fi0 + g; s0 = fmaxf(s0, ALPHA * s0);
                float s1 = fi1 + g; s1 = fmaxf(s1, ALPHA * s1);
                float p0 = ((mb0 >> t) & 1u) ? EXP2F(s0 - mi0) : 0.f;
                float p1 = ((mb1 >> t) & 1u) ? EXP2F(s1 - mi1) : 0.f;
                aF0[t] = (_Float16)p0;
                aF1[t] = (_Float16)p1;
            }

            a00 = __builtin_amdgcn_mfma_f32_16x16x32_f16(aF0, b0, a00, 0, 0, 0);
            a01 = __builtin_amdgcn_mfma_f32_16x16x32_f16(aF0, b1, a01, 0, 0, 0);
            a02 = __builtin_amdgcn_mfma_f32_16x16x32_f16(aF0, b2, a02, 0, 0, 0);
            a03 = __builtin_amdgcn_mfma_f32_16x16x32_f16(aF0, b3, a03, 0, 0, 0);
            a10 = __builtin_amdgcn_mfma_f32_16x16x32_f16(aF1, b0, a10, 0, 0, 0);
            a11 = __builtin_amdgcn_mfma_f32_16x16x32_f16(aF1, b1, a11, 0, 0, 0);
            a12 = __builtin_amdgcn_mfma_f32_16x16x32_f16(aF1, b2, a12, 0, 0, 0);
            a13 = __builtin_amdgcn_mfma_f32_16x16x32_f16(aF1, b3, a13, 0, 0, 0);
            s0acc = __builtin_amdgcn_mfma_f32_16x16x32_f16(aF0, ones, s0acc, 0, 0, 0);
            s1acc = __builtin_amdgcn_mfma_f32_16x16x32_f16(aF1, ones, s1acc, 0, 0, 0);
        }
    }

    // per-wave row sums from ones-MFMA: C[row][col] = rowsum, all cols equal
    if (mrow == 0) {
#pragma unroll
        for (int reg = 0; reg < 4; ++reg) {
            rsp[wsl * 32 + quad * 4 + reg]      = s0acc[reg];
            rsp[wsl * 32 + 16 + quad * 4 + reg] = s1acc[reg];
        }
    }

#pragma unroll
    for (int reg = 0; reg < 4; ++reg) {
        const int r0 = quad * 4 + reg;
        float* d0 = &redacc[(wsl * 32 + r0) * RSTR];
        d0[mrow]      = a00[reg];
        d0[16 + mrow] = a01[reg];
        d0[32 + mrow] = a02[reg];
        d0[48 + mrow] = a03[reg];
        float* d1 = &redacc[(wsl * 32 + 16 + r0) * RSTR];
        d1[mrow]      = a10[reg];
        d1[16 + mrow] = a11[reg];
        d1[32 + mrow] = a12[reg];
        d1[48 + mrow] = a13[reg];
    }
    __syncthreads();

    const int col  = tid & 63;
    const int rgrp = tid >> 6;
#pragma unroll
    for (int rr = 0; rr < 8; ++rr) {
        const int row = rgrp * 8 + rr;
        float sum = redacc[(row) * RSTR + col]
                  + redacc[(32 + row) * RSTR + col]
                  + redacc[(64 + row) * RSTR + col]
                  + redacc[(96 + row) * RSTR + col];
        float den = rsp[row] + rsp[32 + row] + rsp[64 + row] + rsp[96 + row];
        out[((size_t)b * N + i0 + row) * F_OUT + col] = sum / den;
    }
}

extern "C" void kernel_launch(void* const* d_in, const int* in_sizes, int n_in,
                              void* d_out, int out_size, void* d_ws, size_t ws_size,
                              hipStream_t stream) {
    const float* h   = (const float*)d_in[0];
    const float* adj = (const float*)d_in[1];
    const float* W   = (const float*)d_in[2];
    const float* a   = (const float*)d_in[3];
    float* out = (float*)d_out;

    char* ws = (char*)d_ws;
    _Float16* Wpack = (_Float16*)ws;                      // 2 MB
    float* fv = (float*)(ws + (size_t)B * F_OUT * N * 2); // 64 KB
    float* gv = fv + (size_t)B * N;                       // 64 KB
    unsigned* bits = (unsigned*)(gv + (size_t)B * N);     // 512 KB

    fused_pre_kernel<<<dim3(N + B * N / 16), 256, 0, stream>>>(
        adj, bits, h, W, a, Wpack, fv, gv);
    attn_mfma_kernel<<<dim3(N / 32, B), 256, 0, stream>>>(Wpack, fv, gv, bits, out);
}

// Round 11
// 103.511 us; speedup vs baseline: 1.0915x; 1.0915x over previous
//
#include <hip/hip_runtime.h>
#include <hip/hip_bf16.h>
#include <math.h>

#define B 8
#define N 2048
#define F_IN 128
#define F_OUT 64
#define ALPHA 0.2f

typedef _Float16 half8 __attribute__((ext_vector_type(8)));
typedef float f32x4 __attribute__((ext_vector_type(4)));

// ---------------------------------------------------------------------------
// Kernel 1: adj -> bitmask. Block 0 additionally packs W into f16 MFMA
// B-fragment order (Wfrag) and computes wa1[k]=W[k,:]·a1, wa2[k]=W[k,:]·a2.
// ---------------------------------------------------------------------------
__global__ __launch_bounds__(256) void bitmask_kernel(
    const float* __restrict__ adj, unsigned* __restrict__ bits,
    const float* __restrict__ W, const float* __restrict__ a,
    _Float16* __restrict__ Wfrag, float* __restrict__ wa)
{
    const int i = blockIdx.x;
    const int tid = threadIdx.x;
    const int lane = tid & 63;
    const int w = tid >> 6;
    const float* row = adj + (size_t)i * N;
#pragma unroll
    for (int jt = 0; jt < 8; ++jt) {
        float v = row[jt * 256 + tid];
        unsigned long long m = __ballot(v > 0.f);
        if (lane == 0) {
            bits[i * 64 + jt * 8 + w * 2]     = (unsigned)m;
            bits[i * 64 + jt * 8 + w * 2 + 1] = (unsigned)(m >> 32);
        }
    }

    if (blockIdx.x == 0) {
        // W -> f16 fragment order: element (k,f) at
        //   Wfrag[((ks*4+fg)*64 + ((k>>3)&3)*16 + (f&15))*8 + (k&7)]
#pragma unroll
        for (int u = 0; u < 32; ++u) {
            int o    = tid * 32 + u;
            int slot = o & 7;
            int ln   = (o >> 3) & 63;
            int fg   = (o >> 9) & 3;
            int ks   = o >> 11;
            int k    = ks * 32 + (ln >> 4) * 8 + slot;
            int f    = fg * 16 + (ln & 15);
            Wfrag[o] = (_Float16)W[k * 64 + f];
        }
        // wa[0..127] = W @ a1, wa[128..255] = W @ a2 (fp32)
        const int k = tid & 127;
        const float* ap = a + (tid >> 7) * 64;
        float s = 0.f;
#pragma unroll
        for (int f = 0; f < 64; ++f) s += W[k * 64 + f] * ap[f];
        wa[(tid >> 7) * 128 + k] = s;
    }
}

// ---------------------------------------------------------------------------
// Kernel 2: Wh via MFMA -> Wpack fragment order. 1024 blocks x 16 rows,
// 4 waves/block (wave = one 16-feature group, 4 MFMAs). f/g fp32 on wave 0.
// ---------------------------------------------------------------------------
__global__ __launch_bounds__(256) void wh_fg_t_kernel(
    const float* __restrict__ h, const _Float16* __restrict__ Wfrag,
    const float* __restrict__ wa, _Float16* __restrict__ Wpack,
    float* __restrict__ fv, float* __restrict__ gv)
{
    const int tid  = threadIdx.x;
    const int w    = tid >> 6;     // wave = feature group fg
    const int lane = tid & 63;
    const int mrow = lane & 15;
    const int quad = lane >> 4;

    __shared__ float hs[16 * 132];   // 8.4 KB, pad 132

    // stage 16 h-rows (8 KB) coalesced: 512 float4, 2 per thread
    const float4* h4 = (const float4*)(h + (size_t)blockIdx.x * 16 * F_IN);
#pragma unroll
    for (int s = 0; s < 2; ++s) {
        int idx = s * 256 + tid;
        *(float4*)&hs[(idx >> 5) * 132 + (idx & 31) * 4] = h4[idx];
    }

    // this wave's W fragments (4 x half8 = 16 VGPRs), L2-hot broadcast
    half8 wF[4];
#pragma unroll
    for (int ks = 0; ks < 4; ++ks)
        wF[ks] = *(const half8*)(Wfrag + (((ks * 4 + w) * 64) + lane) * 8);

    __syncthreads();

    const int jgl = blockIdx.x * 16;
    const int b   = jgl >> 11;
    const int jb  = jgl & (N - 1);
    const float* hrow = &hs[mrow * 132];

    // MFMA: A row = mrow (h-row), k = ks*32 + quad*8 + t
    f32x4 acc = {0.f, 0.f, 0.f, 0.f};
#pragma unroll
    for (int ks = 0; ks < 4; ++ks) {
        const float* hp = hrow + ks * 32 + quad * 8;
        float4 x0 = *(const float4*)hp;
        float4 x1 = *(const float4*)(hp + 4);
        half8 aF;
#pragma unroll
        for (int t = 0; t < 4; ++t) {
            aF[t]     = (_Float16)((const float*)&x0)[t];
            aF[4 + t] = (_Float16)((const float*)&x1)[t];
        }
        acc = __builtin_amdgcn_mfma_f32_16x16x32_f16(aF, wF[ks], acc, 0, 0, 0);
    }

    // f/g: wave 0 only; row = mrow, k-chunk = quad*32 (fp32 exact)
    if (w == 0) {
        const float* hp = hrow + quad * 32;
        const float* w1 = wa + quad * 32;
        const float* w2 = wa + 128 + quad * 32;
        float s1 = 0.f, s2 = 0.f;
#pragma unroll
        for (int t = 0; t < 32; ++t) {
            float hv = hp[t];
            s1 += hv * w1[t];
            s2 += hv * w2[t];
        }
        s1 += __shfl_xor(s1, 16, 64); s1 += __shfl_xor(s1, 32, 64);
        s2 += __shfl_xor(s2, 16, 64); s2 += __shfl_xor(s2, 32, 64);
        if (lane < 16) {
            fv[(size_t)b * N + jb + lane] = s1;
            gv[(size_t)b * N + jb + lane] = s2;
        }
    }

    // store Wpack: j = jb + quad*4 + reg, f = w*16 + mrow
    const int m     = jb >> 7;
    const int q     = (jb >> 5) & 3;
    const int jg    = (jb & 31) + quad * 4;
    const int flane = ((jg >> 3) & 3) * 16 + mrow;
    const int slot  = jg & 7;
    _Float16* base = Wpack + ((((size_t)b * 16 + m) * 4 + q) * 4 + w) * 512
                     + (size_t)flane * 8 + slot;
    union { _Float16 hh[4]; ushort4 u; } pk;
#pragma unroll
    for (int reg = 0; reg < 4; ++reg) pk.hh[reg] = (_Float16)acc[reg];
    *(ushort4*)(base) = pk.u;
}

// ---------------------------------------------------------------------------
// Kernel 3: barrier-free MFMA main loop. Cross-wave reduction into a SINGLE
// 8.7 KB buffer via 4 barrier-serialized wave phases (no atomics):
// LDS 52->26 KB => blocks/CU 3->~6 (occupancy probe; numerics unchanged
// modulo fp32 add order).
// ---------------------------------------------------------------------------
#define MSTR 68
#define RSTR 68

__global__ __launch_bounds__(256) void attn_mfma_kernel(
    const _Float16* __restrict__ Wpack, const float* __restrict__ fv,
    const float* __restrict__ gv, const unsigned* __restrict__ bits,
    float* __restrict__ out)
{
    const int i0 = blockIdx.x * 32;
    const int b  = blockIdx.y;
    const int tid  = threadIdx.x;
    const int lane = tid & 63;
    const int wsl  = tid >> 6;
    const int mrow = lane & 15;
    const int quad = lane >> 4;

    __shared__ __align__(16) float    gs[N];             // 8 KB
    __shared__ float    fs[32];
    __shared__ float    ms[32];
    __shared__ __align__(16) unsigned mws[32 * MSTR];    // 8.7 KB
    __shared__ float    redacc[32 * RSTR];               // 8.7 KB (shared acc)
    __shared__ float    rsp[4 * 32];                     // per-wave row sums

    const float4* g4 = (const float4*)(gv + (size_t)b * N);
    ((float4*)gs)[tid]       = g4[tid];
    ((float4*)gs)[tid + 256] = g4[tid + 256];
    if (tid < 32) fs[tid] = fv[(size_t)b * N + i0 + tid];
#pragma unroll
    for (int s = 0; s < 2; ++s) {
        const int idx = tid + s * 256;
        const int i   = idx >> 4;
        const int w4  = (idx & 15) * 4;
        *(uint4*)&mws[i * MSTR + w4] =
            *(const uint4*)&bits[(size_t)(i0 + i) * 64 + w4];
    }
    __syncthreads();

#pragma unroll
    for (int rr = 0; rr < 2; ++rr) {
        const int ii = rr * 16 + (tid >> 4);
        const int jj = tid & 15;
        float gmax = -INFINITY;
#pragma unroll
        for (int t = 0; t < 4; ++t) {
            unsigned mw = mws[ii * MSTR + jj * 4 + t];
            const int jb = jj * 128 + t * 32;
            while (mw) {
                int bit = __builtin_ctz(mw);
                gmax = fmaxf(gmax, gs[jb + bit]);
                mw &= mw - 1;
            }
        }
#pragma unroll
        for (int off = 8; off >= 1; off >>= 1)
            gmax = fmaxf(gmax, __shfl_down(gmax, off, 16));
        if (jj == 0) {
            float m = fs[ii] + gmax;
            ms[ii] = (m > 0.f) ? m : ALPHA * m;
        }
    }
    __syncthreads();

    const float fi0 = fs[mrow],      mi0 = ms[mrow];
    const float fi1 = fs[16 + mrow], mi1 = ms[16 + mrow];
    const _Float16* wpb = Wpack + (size_t)b * 131072;

    f32x4 a00 = {0,0,0,0}, a01 = {0,0,0,0}, a02 = {0,0,0,0}, a03 = {0,0,0,0};
    f32x4 a10 = {0,0,0,0}, a11 = {0,0,0,0}, a12 = {0,0,0,0}, a13 = {0,0,0,0};
    float psum0 = 0.f, psum1 = 0.f;

    for (int mm = 0; mm < 4; ++mm) {
        const int m  = wsl * 4 + mm;
        const uint4 mv0 = *(const uint4*)&mws[mrow * MSTR + m * 4];
        const uint4 mv1 = *(const uint4*)&mws[(16 + mrow) * MSTR + m * 4];
#pragma unroll
        for (int q = 0; q < 4; ++q) {
            const int jb = m * 128 + q * 32 + quad * 8;
            const _Float16* tb = wpb + (size_t)(m * 4 + q) * 2048 + lane * 8;

            half8 b0 = *(const half8*)(tb);
            half8 b1 = *(const half8*)(tb + 512);
            half8 b2 = *(const half8*)(tb + 1024);
            half8 b3 = *(const half8*)(tb + 1536);

            const unsigned w0 = (q == 0) ? mv0.x : (q == 1) ? mv0.y
                               : (q == 2) ? mv0.z : mv0.w;
            const unsigned w1 = (q == 0) ? mv1.x : (q == 1) ? mv1.y
                               : (q == 2) ? mv1.z : mv1.w;
            const unsigned mb0 = (w0 >> (quad * 8)) & 0xFFu;
            const unsigned mb1 = (w1 >> (quad * 8)) & 0xFFu;

            float4 ga = *(const float4*)&gs[jb];
            float4 gb = *(const float4*)&gs[jb + 4];
            half8 aF0, aF1;
#pragma unroll
            for (int t = 0; t < 8; ++t) {
                float g = (t < 4) ? ((const float*)&ga)[t]
                                  : ((const float*)&gb)[t - 4];
                float s0 = fi0 + g; s0 = fmaxf(s0, ALPHA * s0);
                float s1 = fi1 + g; s1 = fmaxf(s1, ALPHA * s1);
                float p0 = ((mb0 >> t) & 1u) ? __expf(s0 - mi0) : 0.f;
                float p1 = ((mb1 >> t) & 1u) ? __expf(s1 - mi1) : 0.f;
                _Float16 h0 = (_Float16)p0, h1 = (_Float16)p1;
                aF0[t] = h0; aF1[t] = h1;
                psum0 += (float)h0; psum1 += (float)h1;
            }

            a00 = __builtin_amdgcn_mfma_f32_16x16x32_f16(aF0, b0, a00, 0, 0, 0);
            a01 = __builtin_amdgcn_mfma_f32_16x16x32_f16(aF0, b1, a01, 0, 0, 0);
            a02 = __builtin_amdgcn_mfma_f32_16x16x32_f16(aF0, b2, a02, 0, 0, 0);
            a03 = __builtin_amdgcn_mfma_f32_16x16x32_f16(aF0, b3, a03, 0, 0, 0);
            a10 = __builtin_amdgcn_mfma_f32_16x16x32_f16(aF1, b0, a10, 0, 0, 0);
            a11 = __builtin_amdgcn_mfma_f32_16x16x32_f16(aF1, b1, a11, 0, 0, 0);
            a12 = __builtin_amdgcn_mfma_f32_16x16x32_f16(aF1, b2, a12, 0, 0, 0);
            a13 = __builtin_amdgcn_mfma_f32_16x16x32_f16(aF1, b3, a13, 0, 0, 0);
        }
    }

    // per-wave row sums (quads hold disjoint j's)
    psum0 += __shfl_xor(psum0, 16, 64);
    psum0 += __shfl_xor(psum0, 32, 64);
    psum1 += __shfl_xor(psum1, 16, 64);
    psum1 += __shfl_xor(psum1, 32, 64);
    if (lane < 16) {
        rsp[wsl * 32 + lane]      = psum0;
        rsp[wsl * 32 + 16 + lane] = psum1;
    }

    // cross-wave C reduction: 4 barrier-serialized phases into one buffer
#pragma unroll
    for (int wph = 0; wph < 4; ++wph) {
        if (wsl == wph) {
#pragma unroll
            for (int reg = 0; reg < 4; ++reg) {
                const int r0 = quad * 4 + reg;
                float* d0 = &redacc[r0 * RSTR];
                float* d1 = &redacc[(16 + r0) * RSTR];
                if (wph == 0) {
                    d0[mrow]      = a00[reg];
                    d0[16 + mrow] = a01[reg];
                    d0[32 + mrow] = a02[reg];
                    d0[48 + mrow] = a03[reg];
                    d1[mrow]      = a10[reg];
                    d1[16 + mrow] = a11[reg];
                    d1[32 + mrow] = a12[reg];
                    d1[48 + mrow] = a13[reg];
                } else {
                    d0[mrow]      += a00[reg];
                    d0[16 + mrow] += a01[reg];
                    d0[32 + mrow] += a02[reg];
                    d0[48 + mrow] += a03[reg];
                    d1[mrow]      += a10[reg];
                    d1[16 + mrow] += a11[reg];
                    d1[32 + mrow] += a12[reg];
                    d1[48 + mrow] += a13[reg];
                }
            }
        }
        __syncthreads();
    }

    const int col  = tid & 63;
    const int rgrp = tid >> 6;
#pragma unroll
    for (int rr = 0; rr < 8; ++rr) {
        const int row = rgrp * 8 + rr;
        float den = rsp[row] + rsp[32 + row] + rsp[64 + row] + rsp[96 + row];
        out[((size_t)b * N + i0 + row) * F_OUT + col] =
            redacc[row * RSTR + col] / den;
    }
}

extern "C" void kernel_launch(void* const* d_in, const int* in_sizes, int n_in,
                              void* d_out, int out_size, void* d_ws, size_t ws_size,
                              hipStream_t stream) {
    const float* h   = (const float*)d_in[0];
    const float* adj = (const float*)d_in[1];
    const float* W   = (const float*)d_in[2];
    const float* a   = (const float*)d_in[3];
    float* out = (float*)d_out;

    char* ws = (char*)d_ws;
    _Float16* Wpack = (_Float16*)ws;                      // 2 MB
    float* fv = (float*)(ws + (size_t)B * F_OUT * N * 2); // 64 KB
    float* gv = fv + (size_t)B * N;                       // 64 KB
    unsigned* bits = (unsigned*)(gv + (size_t)B * N);     // 512 KB
    _Float16* Wfrag = (_Float16*)((char*)bits + (size_t)N * 64 * 4); // 16 KB
    float* wa = (float*)(Wfrag + 8192);                   // 1 KB

    bitmask_kernel<<<dim3(N), 256, 0, stream>>>(adj, bits, W, a, Wfrag, wa);
    wh_fg_t_kernel<<<dim3(B * N / 16), 256, 0, stream>>>(h, Wfrag, wa, Wpack, fv, gv);
    attn_mfma_kernel<<<dim3(N / 32, B), 256, 0, stream>>>(Wpack, fv, gv, bits, out);
}

// Round 12
// 101.254 us; speedup vs baseline: 1.1159x; 1.0223x over previous
//
#include <hip/hip_runtime.h>
#include <hip/hip_bf16.h>
#include <math.h>

#define B 8
#define N 2048
#define F_IN 128
#define F_OUT 64
#define ALPHA 0.2f
#define LOG2E 1.4426950408889634f

#if __has_builtin(__builtin_amdgcn_exp2f)
#define EXP2F(x) __builtin_amdgcn_exp2f(x)
#else
#define EXP2F(x) exp2f(x)
#endif

typedef _Float16 half8 __attribute__((ext_vector_type(8)));
typedef float f32x4 __attribute__((ext_vector_type(4)));

// ---------------------------------------------------------------------------
// Kernel 1: adj -> bitmask. Block 0 additionally packs W into f16 MFMA
// B-fragment order (Wfrag) and computes wa1[k]=W[k,:]·a1, wa2[k]=W[k,:]·a2.
// (byte-identical to round 7)
// ---------------------------------------------------------------------------
__global__ __launch_bounds__(256) void bitmask_kernel(
    const float* __restrict__ adj, unsigned* __restrict__ bits,
    const float* __restrict__ W, const float* __restrict__ a,
    _Float16* __restrict__ Wfrag, float* __restrict__ wa)
{
    const int i = blockIdx.x;
    const int tid = threadIdx.x;
    const int lane = tid & 63;
    const int w = tid >> 6;
    const float* row = adj + (size_t)i * N;
#pragma unroll
    for (int jt = 0; jt < 8; ++jt) {
        float v = row[jt * 256 + tid];
        unsigned long long m = __ballot(v > 0.f);
        if (lane == 0) {
            bits[i * 64 + jt * 8 + w * 2]     = (unsigned)m;
            bits[i * 64 + jt * 8 + w * 2 + 1] = (unsigned)(m >> 32);
        }
    }

    if (blockIdx.x == 0) {
#pragma unroll
        for (int u = 0; u < 32; ++u) {
            int o    = tid * 32 + u;
            int slot = o & 7;
            int ln   = (o >> 3) & 63;
            int fg   = (o >> 9) & 3;
            int ks   = o >> 11;
            int k    = ks * 32 + (ln >> 4) * 8 + slot;
            int f    = fg * 16 + (ln & 15);
            Wfrag[o] = (_Float16)W[k * 64 + f];
        }
        const int k = tid & 127;
        const float* ap = a + (tid >> 7) * 64;
        float s = 0.f;
#pragma unroll
        for (int f = 0; f < 64; ++f) s += W[k * 64 + f] * ap[f];
        wa[(tid >> 7) * 128 + k] = s;
    }
}

// ---------------------------------------------------------------------------
// Kernel 2: Wh via MFMA -> Wpack fragment order. 1024 blocks x 16 rows,
// 4 waves/block. f/g fp32 on wave 0. (byte-identical to round 7)
// ---------------------------------------------------------------------------
__global__ __launch_bounds__(256) void wh_fg_t_kernel(
    const float* __restrict__ h, const _Float16* __restrict__ Wfrag,
    const float* __restrict__ wa, _Float16* __restrict__ Wpack,
    float* __restrict__ fv, float* __restrict__ gv)
{
    const int tid  = threadIdx.x;
    const int w    = tid >> 6;     // wave = feature group fg
    const int lane = tid & 63;
    const int mrow = lane & 15;
    const int quad = lane >> 4;

    __shared__ float hs[16 * 132];   // 8.4 KB, pad 132

    const float4* h4 = (const float4*)(h + (size_t)blockIdx.x * 16 * F_IN);
#pragma unroll
    for (int s = 0; s < 2; ++s) {
        int idx = s * 256 + tid;
        *(float4*)&hs[(idx >> 5) * 132 + (idx & 31) * 4] = h4[idx];
    }

    half8 wF[4];
#pragma unroll
    for (int ks = 0; ks < 4; ++ks)
        wF[ks] = *(const half8*)(Wfrag + (((ks * 4 + w) * 64) + lane) * 8);

    __syncthreads();

    const int jgl = blockIdx.x * 16;
    const int b   = jgl >> 11;
    const int jb  = jgl & (N - 1);
    const float* hrow = &hs[mrow * 132];

    f32x4 acc = {0.f, 0.f, 0.f, 0.f};
#pragma unroll
    for (int ks = 0; ks < 4; ++ks) {
        const float* hp = hrow + ks * 32 + quad * 8;
        float4 x0 = *(const float4*)hp;
        float4 x1 = *(const float4*)(hp + 4);
        half8 aF;
#pragma unroll
        for (int t = 0; t < 4; ++t) {
            aF[t]     = (_Float16)((const float*)&x0)[t];
            aF[4 + t] = (_Float16)((const float*)&x1)[t];
        }
        acc = __builtin_amdgcn_mfma_f32_16x16x32_f16(aF, wF[ks], acc, 0, 0, 0);
    }

    if (w == 0) {
        const float* hp = hrow + quad * 32;
        const float* w1 = wa + quad * 32;
        const float* w2 = wa + 128 + quad * 32;
        float s1 = 0.f, s2 = 0.f;
#pragma unroll
        for (int t = 0; t < 32; ++t) {
            float hv = hp[t];
            s1 += hv * w1[t];
            s2 += hv * w2[t];
        }
        s1 += __shfl_xor(s1, 16, 64); s1 += __shfl_xor(s1, 32, 64);
        s2 += __shfl_xor(s2, 16, 64); s2 += __shfl_xor(s2, 32, 64);
        if (lane < 16) {
            fv[(size_t)b * N + jb + lane] = s1;
            gv[(size_t)b * N + jb + lane] = s2;
        }
    }

    const int m     = jb >> 7;
    const int q     = (jb >> 5) & 3;
    const int jg    = (jb & 31) + quad * 4;
    const int flane = ((jg >> 3) & 3) * 16 + mrow;
    const int slot  = jg & 7;
    _Float16* base = Wpack + ((((size_t)b * 16 + m) * 4 + q) * 4 + w) * 512
                     + (size_t)flane * 8 + slot;
    union { _Float16 hh[4]; ushort4 u; } pk;
#pragma unroll
    for (int reg = 0; reg < 4; ++reg) pk.hh[reg] = (_Float16)acc[reg];
    *(ushort4*)(base) = pk.u;
}

// ---------------------------------------------------------------------------
// Kernel 3: barrier-free MFMA aggregation (round-7 structure) with two
// cycle cuts: exp2-domain softmax (f/g pre-scaled by log2e) and row sums
// via ones-column MFMA (removes psum cvt+add chain).
// ---------------------------------------------------------------------------
#define MSTR 68
#define RSTR 68

__global__ __launch_bounds__(256) void attn_mfma_kernel(
    const _Float16* __restrict__ Wpack, const float* __restrict__ fv,
    const float* __restrict__ gv, const unsigned* __restrict__ bits,
    float* __restrict__ out)
{
    const int i0 = blockIdx.x * 32;
    const int b  = blockIdx.y;
    const int tid  = threadIdx.x;
    const int lane = tid & 63;
    const int wsl  = tid >> 6;
    const int mrow = lane & 15;
    const int quad = lane >> 4;

    __shared__ __align__(16) float    gs[N];
    __shared__ float    fs[32];
    __shared__ float    ms[32];
    __shared__ __align__(16) unsigned mws[32 * MSTR];
    __shared__ float    redacc[4 * 32 * RSTR];
    __shared__ float    rsp[4 * 32];

    // stage g,f pre-scaled by log2e (leaky commutes with positive scale)
    const float4* g4 = (const float4*)(gv + (size_t)b * N);
#pragma unroll
    for (int s = 0; s < 2; ++s) {
        float4 gvv = g4[tid + s * 256];
        gvv.x *= LOG2E; gvv.y *= LOG2E; gvv.z *= LOG2E; gvv.w *= LOG2E;
        ((float4*)gs)[tid + s * 256] = gvv;
    }
    if (tid < 32) fs[tid] = fv[(size_t)b * N + i0 + tid] * LOG2E;
#pragma unroll
    for (int s = 0; s < 2; ++s) {
        const int idx = tid + s * 256;
        const int i   = idx >> 4;
        const int w4  = (idx & 15) * 4;
        *(uint4*)&mws[i * MSTR + w4] =
            *(const uint4*)&bits[(size_t)(i0 + i) * 64 + w4];
    }
    __syncthreads();

#pragma unroll
    for (int rr = 0; rr < 2; ++rr) {
        const int ii = rr * 16 + (tid >> 4);
        const int jj = tid & 15;
        float gmax = -INFINITY;
#pragma unroll
        for (int t = 0; t < 4; ++t) {
            unsigned mw = mws[ii * MSTR + jj * 4 + t];
            const int jb = jj * 128 + t * 32;
            while (mw) {
                int bit = __builtin_ctz(mw);
                gmax = fmaxf(gmax, gs[jb + bit]);
                mw &= mw - 1;
            }
        }
#pragma unroll
        for (int off = 8; off >= 1; off >>= 1)
            gmax = fmaxf(gmax, __shfl_down(gmax, off, 16));
        if (jj == 0) {
            float m = fs[ii] + gmax;
            ms[ii] = (m > 0.f) ? m : ALPHA * m;
        }
    }
    __syncthreads();

    const float fi0 = fs[mrow],      mi0 = ms[mrow];
    const float fi1 = fs[16 + mrow], mi1 = ms[16 + mrow];
    const _Float16* wpb = Wpack + (size_t)b * 131072;

    half8 ones;
#pragma unroll
    for (int t = 0; t < 8; ++t) ones[t] = (_Float16)1.0f;

    f32x4 a00 = {0,0,0,0}, a01 = {0,0,0,0}, a02 = {0,0,0,0}, a03 = {0,0,0,0};
    f32x4 a10 = {0,0,0,0}, a11 = {0,0,0,0}, a12 = {0,0,0,0}, a13 = {0,0,0,0};
    f32x4 s0acc = {0,0,0,0}, s1acc = {0,0,0,0};

    for (int mm = 0; mm < 4; ++mm) {
        const int m  = wsl * 4 + mm;
        const uint4 mv0 = *(const uint4*)&mws[mrow * MSTR + m * 4];
        const uint4 mv1 = *(const uint4*)&mws[(16 + mrow) * MSTR + m * 4];
#pragma unroll
        for (int q = 0; q < 4; ++q) {
            const int jb = m * 128 + q * 32 + quad * 8;
            const _Float16* tb = wpb + (size_t)(m * 4 + q) * 2048 + lane * 8;

            half8 b0 = *(const half8*)(tb);
            half8 b1 = *(const half8*)(tb + 512);
            half8 b2 = *(const half8*)(tb + 1024);
            half8 b3 = *(const half8*)(tb + 1536);

            const unsigned w0 = (q == 0) ? mv0.x : (q == 1) ? mv0.y
                               : (q == 2) ? mv0.z : mv0.w;
            const unsigned w1 = (q == 0) ? mv1.x : (q == 1) ? mv1.y
                               : (q == 2) ? mv1.z : mv1.w;
            const unsigned mb0 = (w0 >> (quad * 8)) & 0xFFu;
            const unsigned mb1 = (w1 >> (quad * 8)) & 0xFFu;

            float4 ga = *(const float4*)&gs[jb];
            float4 gb = *(const float4*)&gs[jb + 4];
            half8 aF0, aF1;
#pragma unroll
            for (int t = 0; t < 8; ++t) {
                float g = (t < 4) ? ((const float*)&ga)[t]
                                  : ((const float*)&gb)[t - 4];
                float s0 = fi0 + g; s0 = fmaxf(s0, ALPHA * s0);
                float s1 = fi1 + g; s1 = fmaxf(s1, ALPHA * s1);
                float p0 = ((mb0 >> t) & 1u) ? EXP2F(s0 - mi0) : 0.f;
                float p1 = ((mb1 >> t) & 1u) ? EXP2F(s1 - mi1) : 0.f;
                aF0[t] = (_Float16)p0;
                aF1[t] = (_Float16)p1;
            }

            a00 = __builtin_amdgcn_mfma_f32_16x16x32_f16(aF0, b0, a00, 0, 0, 0);
            a01 = __builtin_amdgcn_mfma_f32_16x16x32_f16(aF0, b1, a01, 0, 0, 0);
            a02 = __builtin_amdgcn_mfma_f32_16x16x32_f16(aF0, b2, a02, 0, 0, 0);
            a03 = __builtin_amdgcn_mfma_f32_16x16x32_f16(aF0, b3, a03, 0, 0, 0);
            a10 = __builtin_amdgcn_mfma_f32_16x16x32_f16(aF1, b0, a10, 0, 0, 0);
            a11 = __builtin_amdgcn_mfma_f32_16x16x32_f16(aF1, b1, a11, 0, 0, 0);
            a12 = __builtin_amdgcn_mfma_f32_16x16x32_f16(aF1, b2, a12, 0, 0, 0);
            a13 = __builtin_amdgcn_mfma_f32_16x16x32_f16(aF1, b3, a13, 0, 0, 0);
            s0acc = __builtin_amdgcn_mfma_f32_16x16x32_f16(aF0, ones, s0acc, 0, 0, 0);
            s1acc = __builtin_amdgcn_mfma_f32_16x16x32_f16(aF1, ones, s1acc, 0, 0, 0);
        }
    }

    // per-wave row sums from ones-MFMA (all C columns equal; take mrow==0)
    if (mrow == 0) {
#pragma unroll
        for (int reg = 0; reg < 4; ++reg) {
            rsp[wsl * 32 + quad * 4 + reg]      = s0acc[reg];
            rsp[wsl * 32 + 16 + quad * 4 + reg] = s1acc[reg];
        }
    }

#pragma unroll
    for (int reg = 0; reg < 4; ++reg) {
        const int r0 = quad * 4 + reg;
        float* d0 = &redacc[(wsl * 32 + r0) * RSTR];
        d0[mrow]      = a00[reg];
        d0[16 + mrow] = a01[reg];
        d0[32 + mrow] = a02[reg];
        d0[48 + mrow] = a03[reg];
        float* d1 = &redacc[(wsl * 32 + 16 + r0) * RSTR];
        d1[mrow]      = a10[reg];
        d1[16 + mrow] = a11[reg];
        d1[32 + mrow] = a12[reg];
        d1[48 + mrow] = a13[reg];
    }
    __syncthreads();

    const int col  = tid & 63;
    const int rgrp = tid >> 6;
#pragma unroll
    for (int rr = 0; rr < 8; ++rr) {
        const int row = rgrp * 8 + rr;
        float sum = redacc[(row) * RSTR + col]
                  + redacc[(32 + row) * RSTR + col]
                  + redacc[(64 + row) * RSTR + col]
                  + redacc[(96 + row) * RSTR + col];
        float den = rsp[row] + rsp[32 + row] + rsp[64 + row] + rsp[96 + row];
        out[((size_t)b * N + i0 + row) * F_OUT + col] = sum / den;
    }
}

extern "C" void kernel_launch(void* const* d_in, const int* in_sizes, int n_in,
                              void* d_out, int out_size, void* d_ws, size_t ws_size,
                              hipStream_t stream) {
    const float* h   = (const float*)d_in[0];
    const float* adj = (const float*)d_in[1];
    const float* W   = (const float*)d_in[2];
    const float* a   = (const float*)d_in[3];
    float* out = (float*)d_out;

    char* ws = (char*)d_ws;
    _Float16* Wpack = (_Float16*)ws;                      // 2 MB
    float* fv = (float*)(ws + (size_t)B * F_OUT * N * 2); // 64 KB
    float* gv = fv + (size_t)B * N;                       // 64 KB
    unsigned* bits = (unsigned*)(gv + (size_t)B * N);     // 512 KB
    _Float16* Wfrag = (_Float16*)((char*)bits + (size_t)N * 64 * 4); // 16 KB
    float* wa = (float*)(Wfrag + 8192);                   // 1 KB

    bitmask_kernel<<<dim3(N), 256, 0, stream>>>(adj, bits, W, a, Wfrag, wa);
    wh_fg_t_kernel<<<dim3(B * N / 16), 256, 0, stream>>>(h, Wfrag, wa, Wpack, fv, gv);
    attn_mfma_kernel<<<dim3(N / 32, B), 256, 0, stream>>>(Wpack, fv, gv, bits, out);
}